// Round 13
// baseline (236.555 us; speedup 1.0000x reference)
//
#include <hip/hip_runtime.h>

#define NTAG 64
#define TLEN 512
#define HALF (TLEN / 2)
#define START_TAG 62
#define STOP_TAG 63
#define CHUNK 32          // timesteps staged per LDS buffer

// One workgroup (128 thr = 2 waves) per batch. wave0: fwd consumes w_0..255;
// wave1: bwd seeds z=S*w_511, steps w_510..256, one bare E^T matvec.
// Linear domain; exact pow2 renorm every step (zero-guarded, ref = tag 0).
//
// Round-13: SYSTOLIC matvec — the state never leaves registers. Rounds 5-12
// proved the LDS-broadcast family floors at ~650-800 cyc/step (write->read
// seam + 16 ds_read_b128 on a DS pipe shared by 4 waves/CU). Here the
// all-to-all broadcast is 62 DPP wavefront rotations (wf_rol1/wf_ror1, two
// chains rotating opposite directions, 32 links each) with skew-indexed E:
//   Ea[i] = E[lane][(lane+s*i)&63], Eb[i] = E[lane][(lane-s*i)&63]
// (static VGPR indices; s probed at runtime from the HW rotate direction).
// Per step: 63 dpp + 64 fma + ~8 misc = ~270 cyc issue, no DS in the chain.
__global__ __launch_bounds__(128) void crf_fwd_bwd(
    const float* __restrict__ emis,   // [B, T, L]
    const float* __restrict__ trans,  // [L, L]  trans[next, prev]
    float* __restrict__ out)          // [B]
{
    const int b    = blockIdx.x;
    const int tid  = threadIdx.x;
    const int lane = tid & 63;
    const int w    = tid >> 6;  // 0 = fwd, 1 = bwd

    __shared__ float lds[2 * 2 * CHUNK * NTAG];   // staged w = exp(emis), 32 KB
    __shared__ float shv[2][NTAG];

    const float L2E = 1.4426950408889634f;
    const float LN2 = 0.6931471805599453f;

    // wavefront rotate by one lane, both directions (DPP, gfx9 encodings)
    #define ROL1(v) __uint_as_float(__builtin_amdgcn_update_dpp(              \
        __float_as_uint(v), __float_as_uint(v), 0x134, 0xf, 0xf, false))
    #define ROR1(v) __uint_as_float(__builtin_amdgcn_update_dpp(              \
        __float_as_uint(v), __float_as_uint(v), 0x13C, 0xf, 0xf, false))

    // probe the HW rotate direction: after one ROL, lane0 holds lane s (s=+1)
    // or lane 63 (s=-1); after i ROLs lane L holds x[(L + s*i) & 63].
    int pr  = __builtin_amdgcn_update_dpp(0, lane, 0x134, 0xf, 0xf, false);
    int d0  = __builtin_amdgcn_readfirstlane(pr);
    int sgn = (d0 == 1) ? 1 : -1;

    // E = exp(trans) with systolic skew. fwd reduces over prev (row lane of
    // trans), bwd over next (column lane). Masked (-10000) -> exactly 0.
    #define TRV(r, c) ((w == 0) ? trans[(r) * NTAG + (c)] : trans[(c) * NTAG + (r)])
    float Ea[33], Eb[32];
    #pragma unroll
    for (int i = 1; i <= 32; ++i) {
        int ia = (lane + sgn * i) & 63;
        Ea[i] = exp2f(TRV(lane, ia) * L2E);
    }
    #pragma unroll
    for (int i = 1; i <= 31; ++i) {
        int ib = (lane - sgn * i) & 63;
        Eb[i] = exp2f(TRV(lane, ib) * L2E);
    }
    float Ez = exp2f(TRV(lane, lane) * L2E);   // offset 0

    const float* eb = emis + (size_t)b * TLEN * NTAG;

    // ---- chunk staging (round-8 proven): 8 float4/lane per 32-step chunk ----
    float4 r0, r1, r2, r3, r4, r5, r6, r7;
    #define LOAD_CHUNK(baseT)                                        \
        do {                                                         \
            const float4* gp = (const float4*)(eb + (baseT) * NTAG); \
            r0 = gp[0 * 64 + lane]; r1 = gp[1 * 64 + lane];          \
            r2 = gp[2 * 64 + lane]; r3 = gp[3 * 64 + lane];          \
            r4 = gp[4 * 64 + lane]; r5 = gp[5 * 64 + lane];          \
            r6 = gp[6 * 64 + lane]; r7 = gp[7 * 64 + lane];          \
        } while (0)
    #define EXP4(v) make_float4(exp2f((v).x * L2E), exp2f((v).y * L2E), \
                                exp2f((v).z * L2E), exp2f((v).w * L2E))
    #define STORE_CHUNK_EXP(bufp)                                    \
        do {                                                         \
            float4* b4 = (float4*)(bufp);                            \
            b4[0 * 64 + lane] = EXP4(r0); b4[1 * 64 + lane] = EXP4(r1); \
            b4[2 * 64 + lane] = EXP4(r2); b4[3 * 64 + lane] = EXP4(r3); \
            b4[4 * 64 + lane] = EXP4(r4); b4[5 * 64 + lane] = EXP4(r5); \
            b4[6 * 64 + lane] = EXP4(r6); b4[7 * 64 + lane] = EXP4(r7); \
        } while (0)

    // systolic matvec: ssum[lane] = sum_k E[lane,k] x[k]; d_ = renorm shift
    // from tag0 (readfirstlane -> SALU, zero-guarded: fwd seed tag0 == 0).
    #define ROTMV(ssum, d_)                                          \
        do {                                                         \
            unsigned ref_ = __builtin_amdgcn_readfirstlane(__float_as_uint(x)); \
            int ef_ = (int)((ref_ >> 23) & 0xffu);                   \
            d_ = (ef_ == 0) ? 0 : ef_ - 127;                         \
            float xa_ = x, xb_ = x;                                  \
            float a0_ = Ez * x, a1_ = 0.f, a2_ = 0.f, a3_ = 0.f;     \
            _Pragma("unroll")                                        \
            for (int i_ = 1; i_ <= 31; ++i_) {                       \
                xa_ = ROL1(xa_);                                     \
                xb_ = ROR1(xb_);                                     \
                if (i_ & 1) { a1_ = fmaf(Ea[i_], xa_, a1_);          \
                              a3_ = fmaf(Eb[i_], xb_, a3_); }        \
                else        { a2_ = fmaf(Ea[i_], xa_, a2_);          \
                              a0_ = fmaf(Eb[i_], xb_, a0_); }        \
            }                                                        \
            xa_ = ROL1(xa_);                                         \
            a1_ = fmaf(Ea[32], xa_, a1_);                            \
            ssum = (a0_ + a1_) + (a2_ + a3_);                        \
        } while (0)

    // x_new = (E . x) * em * 2^-d  (renorm every step, exact)
    #define STEP(buf, s)                                             \
        do {                                                         \
            float em_ = (buf)[(s) * NTAG + lane];                    \
            float ssum_; int d_;                                     \
            ROTMV(ssum_, d_);                                        \
            off += d_;                                               \
            float rs_ = __uint_as_float((unsigned)(127 - d_) << 23); \
            x = ssum_ * (em_ * rs_);                                 \
        } while (0)

    float x   = 0.0f;
    int   off = 0;   // accumulated power-of-2 offset (exact, lane-uniform)

    if (w == 0) {
        x = (lane == START_TAG) ? 1.0f : 0.0f;   // a_0 = indicator

        LOAD_CHUNK(0);
        #pragma clang loop unroll(disable)
        for (int ci = 0; ci < 8; ++ci) {
            float* buf = &lds[(ci & 1) * (CHUNK * NTAG)];
            STORE_CHUNK_EXP(buf);
            if (ci < 7) LOAD_CHUNK((ci + 1) * CHUNK);   // in flight ~32 steps

            #pragma clang loop unroll_count(4)
            for (int s = 0; s < CHUNK; ++s) STEP(buf, s);  // w_0..w_255
        }
        // x = alpha_255 (linear f32, scaled by 2^off)
    } else {
        float Sv = exp2f(trans[STOP_TAG * NTAG + lane] * L2E);  // exp(trans[STOP,:])

        LOAD_CHUNK(HALF + 7 * CHUNK);
        #pragma clang loop unroll(disable)
        for (int i = 0; i < 8; ++i) {
            float* buf = &lds[(2 + (i & 1)) * (CHUNK * NTAG)];
            STORE_CHUNK_EXP(buf);
            if (i < 7) LOAD_CHUNK(HALF + (6 - i) * CHUNK);

            int s0 = CHUNK - 1;
            if (i == 0) {
                // seed z_511 = S * w_511 (w_511 staged just above)
                x = Sv * buf[(CHUNK - 1) * NTAG + lane];
                s0 = CHUNK - 2;
            }
            #pragma clang loop unroll_count(4)
            for (int s = s0; s >= 0; --s) STEP(buf, s);    // w_510..w_256
        }
        // bare matvec: beta_255 = E^T z_256 (renorm folded, exact)
        {
            float ssum_; int d_;
            ROTMV(ssum_, d_);
            off += d_;
            x = ssum_ * __uint_as_float((unsigned)(127 - d_) << 23);
        }
    }

    // merge the half-chains in log2 domain
    shv[w][lane] = log2f(x) + (float)off;   // -inf for masked tags, safe
    __syncthreads();

    if (w == 0) {
        float v = shv[0][lane] + shv[1][lane];
        float m = v;
        #pragma unroll
        for (int d = 1; d < 64; d <<= 1) m = fmaxf(m, __shfl_xor(m, d, 64));
        float e = exp2f(v - m);
        #pragma unroll
        for (int d = 1; d < 64; d <<= 1) e += __shfl_xor(e, d, 64);
        if (lane == 0) out[b] = LN2 * (m + log2f(e));
    }
}

extern "C" void kernel_launch(void* const* d_in, const int* in_sizes, int n_in,
                              void* d_out, int out_size, void* d_ws, size_t ws_size,
                              hipStream_t stream) {
    const float* emis  = (const float*)d_in[0];   // [512, 512, 64] f32
    const float* trans = (const float*)d_in[1];   // [64, 64] f32
    float* out = (float*)d_out;                   // [512] f32
    (void)in_sizes; (void)n_in; (void)out_size; (void)d_ws; (void)ws_size;
    crf_fwd_bwd<<<512, 128, 0, stream>>>(emis, trans, out);
}